// Round 7
// baseline (45122.806 us; speedup 1.0000x reference)
//
#include <hip/hip_runtime.h>

typedef _Float16 h16;
typedef _Float16 half8 __attribute__((ext_vector_type(8)));
typedef float f32x4 __attribute__((ext_vector_type(4)));

#define NEGV -1000000000.0f
#define MFMA16(a,b,c) __builtin_amdgcn_mfma_f32_16x16x32_f16(a,b,c,0,0,0)

struct Params {
  const float *memory, *dec_in; const int *memlen;
  const float *w1, *w2;
  const float *awih, *awhh, *abih, *abhh;
  const float *qw, *mw, *vw, *lcw, *ldw;
  const float *dwih, *dwhh, *dbih, *dbhh;
  const float *pw, *pb, *gw, *gb;
  float *out, *ws;
};

// ---- ws layout ----
// f16 arrays: offsets in HALFS
constexpr long long XALLF_H = 0;          // 400*32*256  xallf[t][b][256]
constexpr long long PMH_H   = 3276800;    // 32*128*384  pm[b][a][t]
constexpr long long PLB_H   = 4849664;    // 32*384*128  plb[b][t][a]
constexpr long long AWIHF_H = 6422528;    // 4096*768
constexpr long long AWHHF_H = 9568256;    // 4096*1024
constexpr long long DWIHF_H = 13762560;   // 4096*1536
constexpr long long DWHHF_H = 20054016;   // 4096*1024
constexpr long long LCWF_H  = 24248320;   // 32*64 (padded conv wts, f-major)
constexpr long long LDWF_H  = 24250368;   // 128*32 (a-major)
constexpr long long AHF_H   = 24254464;   // 2 * 32*1024 (double buffered)
constexpr long long DHF_H   = 24320000;   // 32*1024
constexpr long long CTXF_H  = 24352768;   // 32*512
// f16 read-only copies of per-step-streamed fp32 tensors (bytes halved):
constexpr long long MEMF_H  = 24812544;   // 32*384*512 memory (f16)
constexpr long long PWF_H   = 31104000;   // 80*1536 proj weights (f16)
constexpr long long QWF_H   = 31226880;   // 128*1024 query weights (f16)
// fp32 arrays: offsets in FLOATS
constexpr long long ZERO_F0 = 12127232;   // zero region start (covers AHF..DPART)
constexpr long long AC_F    = 12184576;   // 32*1024
constexpr long long DC_F    = 12217344;   // 32*1024
constexpr long long AW_F    = 12250112;   // 32*384
constexpr long long AWC_F   = 12262400;   // 32*384
constexpr long long DPART_F = 12274688;   // 32*4096
constexpr long long BAR_F   = 12405760;   // 512 uints
constexpr int  ZERO_LEN = 278528;
constexpr unsigned NBLK = 512;
// out layout
constexpr long long GATE0  = 1024000;
constexpr long long ALIGN0 = 1036800;

union SMem {
  float pmstage[12][512];                                     // 24.6 KB
  struct { float x[5][80]; float l1[5][256]; } pre;
  struct { float red[16][2][16][17]; } g;                     // 34.8 KB (16 waves)
  struct { float awseg[2][128]; h16 im2[96][72]; h16 locT[96][32];
           unsigned p16[96][64]; } ploc;                      // 45.6 KB (max)
  struct { float ah[1024]; float pq[128]; float pqp[8][128]; float vv[128];
           float e[384]; float w[384]; float red[32];
           float ctxred[4][256][2]; } row;                    // ~20 KB
  struct { float hc[1536]; float mp[80][8]; float gacc; } mel;
};

__device__ __forceinline__ float sigf(float x){ return 1.0f/(1.0f+__expf(-x)); }
__device__ __forceinline__ float tanhfast(float x){ float e2 = __expf(2.0f*x); return 1.0f - 2.0f/(e2+1.0f); }

// ---- agent-scope (cross-XCD coherent, cache-bypassing) accessors ----
__device__ __forceinline__ float aldf(const float* p){
  return __hip_atomic_load(p, __ATOMIC_RELAXED, __HIP_MEMORY_SCOPE_AGENT);
}
__device__ __forceinline__ void astf(float* p, float v){
  __hip_atomic_store(p, v, __ATOMIC_RELAXED, __HIP_MEMORY_SCOPE_AGENT);
}
__device__ __forceinline__ unsigned long long aldu64(const h16* p){
  return __hip_atomic_load((const unsigned long long*)p, __ATOMIC_RELAXED, __HIP_MEMORY_SCOPE_AGENT);
}
__device__ __forceinline__ half8 ald16(const h16* p){
  union { unsigned long long q[2]; half8 v; } u;
  u.q[0] = __hip_atomic_load((const unsigned long long*)p,     __ATOMIC_RELAXED, __HIP_MEMORY_SCOPE_AGENT);
  u.q[1] = __hip_atomic_load(((const unsigned long long*)p)+1, __ATOMIC_RELAXED, __HIP_MEMORY_SCOPE_AGENT);
  return u.v;
}
__device__ __forceinline__ void asth(h16* p, float v){
  union { h16 h; unsigned short s; } u; u.h = (h16)v;
  __hip_atomic_store((unsigned short*)p, u.s, __ATOMIC_RELAXED, __HIP_MEMORY_SCOPE_AGENT);
}
__device__ __forceinline__ void astu32(unsigned* p, unsigned v){
  __hip_atomic_store(p, v, __ATOMIC_RELAXED, __HIP_MEMORY_SCOPE_AGENT);
}

// software grid barrier; full=true adds release/acquire cache maintenance
__device__ __forceinline__ void gbar(unsigned* cnts, unsigned ep, bool full){
  __syncthreads();
  if (threadIdx.x == 0){
    if (full) __threadfence();
    __hip_atomic_fetch_add(&cnts[(blockIdx.x & 7)*64], 1u, __ATOMIC_RELEASE, __HIP_MEMORY_SCOPE_AGENT);
    const unsigned tgt = ep*NBLK;
    for (;;){
      unsigned s = 0;
      #pragma unroll
      for (int i = 0; i < 8; ++i)
        s += __hip_atomic_load(&cnts[i*64], __ATOMIC_RELAXED, __HIP_MEMORY_SCOPE_AGENT);
      if (s >= tgt) break;
      __builtin_amdgcn_s_sleep(4);
    }
    if (full) __threadfence();
  }
  __syncthreads();
}

__global__ void init_kernel(float* ws){
  unsigned* c = (unsigned*)(ws + BAR_F);
  if (threadIdx.x < 512) c[threadIdx.x] = 0u;
}

// 1024 threads/block (16 waves): 32 waves/CU at 2 blocks/CU (HW max).
// __launch_bounds__(1024, 8): 8 waves/EU -> VGPR<=64 (round-6 binary already
// compiled at 64 with HALF this split factor, so no spill expected).
// LDS 45.6KB*2 = 91KB < 160KB. Same 512-block grid; barrier unchanged.
__global__ __launch_bounds__(1024, 8)
void decoder_kernel(Params P){
  __shared__ SMem sm;
  const int tid = threadIdx.x;
  const int bid = blockIdx.x;
  float* ws = P.ws;
  h16*   wsh = (h16*)ws;
  unsigned* bar = (unsigned*)(ws + BAR_F);
  unsigned ep = 0;

  const int lane = tid & 63, wv = tid >> 6;          // wv in 0..15
  const int i16 = lane & 15, q = lane >> 4;

  // ============== PROLOGUE ==============
  {
    const long long gtid = (long long)bid*1024 + tid;
    const long long GS = 524288;
    for (long long i = gtid; i < ZERO_LEN; i += GS) ws[ZERO_F0 + i] = 0.f;
    for (long long i = gtid; i < 3145728; i += GS) wsh[AWIHF_H+i] = (h16)P.awih[i];
    for (long long i = gtid; i < 4194304; i += GS) wsh[AWHHF_H+i] = (h16)P.awhh[i];
    for (long long i = gtid; i < 6291456; i += GS) wsh[DWIHF_H+i] = (h16)P.dwih[i];
    for (long long i = gtid; i < 4194304; i += GS) wsh[DWHHF_H+i] = (h16)P.dwhh[i];
    for (long long i = gtid; i < 6291456; i += GS) wsh[MEMF_H+i] = (h16)P.memory[i];
    for (long long i = gtid; i < 122880; i += GS) wsh[PWF_H+i] = (h16)P.pw[i];
    for (long long i = gtid; i < 131072; i += GS) wsh[QWF_H+i] = (h16)P.qw[i];
    for (long long i = gtid; i < 2048; i += GS){
      int f = (int)(i >> 6), kk = (int)(i & 63), ch = kk >> 5, k = kk & 31;
      wsh[LCWF_H+i] = (k < 31) ? (h16)P.lcw[f*62 + ch*31 + k] : (h16)0.f;
    }
    for (long long i = gtid; i < 4096; i += GS) wsh[LDWF_H+i] = (h16)P.ldw[i];
  }
  // processed_memory -> PMH (f16): compute on threads 0..511 (one-time)
  {
    const int b = bid >> 4, part = bid & 15;
    for (int sub = 0; sub < 2; ++sub){
      const int t0 = part*24 + sub*12;
      __syncthreads();
      for (int i = tid; i < 1536; i += 1024){
        int row = i >> 7, c4 = (i & 127) << 2;
        *reinterpret_cast<float4*>(&sm.pmstage[row][c4]) =
          *reinterpret_cast<const float4*>(P.memory + ((long long)(b*384 + t0 + row))*512 + c4);
      }
      __syncthreads();
      if (tid < 512){
        const int a = tid & 127, th = tid >> 7;     // th in 0..3, 3 rows each
        float acc[3] = {0,0,0};
        const float* mwr = P.mw + (long long)a*512;
        for (int e = 0; e < 512; ++e){
          float wvv = mwr[e];
          #pragma unroll
          for (int jj = 0; jj < 3; ++jj) acc[jj] += wvv*sm.pmstage[th*3+jj][e];
        }
        #pragma unroll
        for (int jj = 0; jj < 3; ++jj)
          wsh[PMH_H + ((long long)b*128 + a)*384 + t0 + th*3 + jj] = (h16)acc[jj];
      }
    }
  }
  // prenet -> XALLF (f16): rows 0..255 on threads 0..255 (one-time)
  {
    for (int batch = 0; batch < 5; ++batch){
      const int pbase = bid*25 + batch*5;
      __syncthreads();
      for (int i = tid; i < 400; i += 1024){
        int j = i/80, m = i%80;
        int p = pbase + j; int tq = p >> 5, bb = p & 31;
        float v = 0.f;
        if (tq > 0) v = P.dec_in[((long long)bb*80 + m)*400 + (tq-1)];
        sm.pre.x[j][m] = v;
      }
      __syncthreads();
      {
        float acc[5] = {0,0,0,0,0};
        if (tid < 256){
          const float* w1r = P.w1 + (long long)tid*80;
          for (int m = 0; m < 80; ++m){
            float wvv = w1r[m];
            #pragma unroll
            for (int j = 0; j < 5; ++j) acc[j] += wvv*sm.pre.x[j][m];
          }
        }
        __syncthreads();
        if (tid < 256){
          #pragma unroll
          for (int j = 0; j < 5; ++j) sm.pre.l1[j][tid] = fmaxf(acc[j], 0.f);
        }
      }
      __syncthreads();
      if (tid < 256){
        float acc[5] = {0,0,0,0,0};
        const float* w2r = P.w2 + (long long)tid*256;
        for (int pp = 0; pp < 256; ++pp){
          float wvv = w2r[pp];
          #pragma unroll
          for (int j = 0; j < 5; ++j) acc[j] += wvv*sm.pre.l1[j][pp];
        }
        #pragma unroll
        for (int j = 0; j < 5; ++j){
          int p = pbase + j; int tq = p >> 5, bb = p & 31;
          wsh[XALLF_H + ((long long)tq*32 + bb)*256 + tid] = (h16)fmaxf(acc[j], 0.f);
        }
      }
    }
  }
  gbar(bar, ++ep, true);   // full fence once: weights/PMH/XALLF now visible + cached

  // ============== MAIN LOOP ==============
  for (int t = 0; t <= 400; ++t){
    const int cur = t & 1, prv = (t+1) & 1;

    // ---------- PHASE A ----------
    if (bid < 256){
      // att-LSTM: 4 units/block. 16 waves = 8 K-groups x 2 batch-halves;
      // each wave: 7 K-steps x 1 MFMA.
      if (t < 400){
        const int u0 = bid*4;
        const int w8 = wv & 7, bt = wv >> 3;
        const int n = ((i16 >> 2)*1024) + u0 + (i16 & 3);   // gate-gathered row
        const int row0 = bt*16 + i16;
        f32x4 acc = {0,0,0,0};
        const long long prvO = (long long)prv*32768;
        for (int s = w8*7; s < w8*7 + 7; ++s){
          const int k0 = s*32;
          const h16* pA = (k0 < 768) ? wsh + AWIHF_H + (long long)n*768 + k0 + q*8
                                     : wsh + AWHHF_H + (long long)n*1024 + (k0-768) + q*8;
          half8 A = *(const half8*)pA;
          half8 B;
          if (k0 < 256)      B = *(const half8*)(wsh + XALLF_H + ((long long)t*32 + row0)*256 + k0 + q*8);
          else if (k0 < 768) B = ald16(wsh + CTXF_H + row0*512 + (k0-256) + q*8);
          else               B = ald16(wsh + AHF_H + prvO + (long long)row0*1024 + (k0-768) + q*8);
          acc = MFMA16(A, B, acc);
        }
        #pragma unroll
        for (int r = 0; r < 4; ++r) sm.g.red[w8][bt][q*4+r][i16] = acc[r];
        __syncthreads();
        if (tid < 128){
          const int uu = tid >> 5, b = tid & 31;
          const int bt2 = b >> 4, c = b & 15;
          float g4[4];
          #pragma unroll
          for (int g = 0; g < 4; ++g){
            const int tr = g*4 + uu;
            float v = 0.f;
            #pragma unroll
            for (int w = 0; w < 8; ++w) v += sm.g.red[w][bt2][tr][c];
            const int ng = g*1024 + u0 + uu;
            g4[g] = v + P.abih[ng] + P.abhh[ng];
          }
          const long long idx = (long long)b*1024 + u0 + uu;
          float c2 = sigf(g4[1])*ws[AC_F + idx] + sigf(g4[0])*tanhfast(g4[2]);
          ws[AC_F + idx] = c2;
          asth(wsh + AHF_H + (long long)cur*32768 + idx, sigf(g4[3])*tanhfast(c2));
        }
      }
    } else if (bid < 384){
      // loc conv + dense via MFMA -> plb f16 [b][t][a]
      if (t < 400){
        const int pb = bid - 256, b = pb >> 2, tbase = (pb & 3)*96;
        for (int i = tid; i < 252; i += 1024){
          int ch = i / 126, ix = i % 126;
          int pos = tbase - 15 + ix;
          float v = 0.f;
          if (pos >= 0 && pos < 384)
            v = aldf(ws + (ch ? AWC_F : AW_F) + b*384 + pos);
          sm.ploc.awseg[ch][ix] = v;
        }
        __syncthreads();
        for (int i = tid; i < 96*64; i += 1024){
          int tt = i >> 6, kk = i & 63, ch = kk >> 5, k = kk & 31;
          sm.ploc.im2[tt][kk] = (k < 31) ? (h16)sm.ploc.awseg[ch][tt + k] : (h16)0.f;
        }
        __syncthreads();
        // conv: 12 tiles over 16 waves (4 idle)
        {
          int tile = wv;
          if (tile < 12){
            int tT = tile % 6, tF = tile / 6;
            f32x4 a = {0,0,0,0};
            #pragma unroll
            for (int ks = 0; ks < 2; ++ks){
              half8 A = *(const half8*)&sm.ploc.im2[tT*16 + i16][ks*32 + q*8];
              half8 B = *(const half8*)(wsh + LCWF_H + (tF*16 + i16)*64 + ks*32 + q*8);
              a = MFMA16(A, B, a);
            }
            #pragma unroll
            for (int r = 0; r < 4; ++r)
              sm.ploc.locT[tT*16 + q*4 + r][tF*16 + i16] = (h16)a[r];
          }
        }
        __syncthreads();
        // dense: 48 tiles over 16 waves = 3/wave
        unsigned short* s16 = (unsigned short*)&sm.ploc.p16[0][0];
        #pragma unroll
        for (int p = 0; p < 3; ++p){
          int tile = wv + p*16;
          int tT = tile % 6, tA = tile / 6;
          half8 A = *(const half8*)&sm.ploc.locT[tT*16 + i16][q*8];
          half8 B = *(const half8*)(wsh + LDWF_H + (tA*16 + i16)*32 + q*8);
          f32x4 a = {0,0,0,0};
          a = MFMA16(A, B, a);
          int aa = tA*16 + i16;
          union { unsigned long long u; h16 h[4]; } pmu;
          pmu.u = *(const unsigned long long*)
              (wsh + PMH_H + ((long long)b*128 + aa)*384 + tbase + tT*16 + q*4);
          #pragma unroll
          for (int r = 0; r < 4; ++r){
            union { h16 h; unsigned short s; } cv;
            cv.h = (h16)(a[r] + (float)pmu.h[r]);
            s16[(tT*16 + q*4 + r)*128 + aa] = cv.s;
          }
        }
        __syncthreads();
        unsigned* plbu = (unsigned*)(wsh + PLB_H);
        for (int i = tid; i < 96*64; i += 1024){
          int tt = i >> 6, a2 = i & 63;
          astu32(plbu + ((long long)b*384 + tbase + tt)*64 + a2, sm.ploc.p16[tt][a2]);
        }
      }
    } else {
      // dec-LSTM ctx-part (K=512) + cell for step t-1: 8 units/block.
      // 16 waves = 2 unit-quads x 8 K-eighths; 2 K-steps x 2 MFMA each.
      if (t >= 1){
        const int u0 = (bid-384)*8;
        const int jt = wv & 1, kh = wv >> 1;          // kh in 0..7
        const int n = ((i16 >> 2)*1024) + u0 + jt*4 + (i16 & 3);
        f32x4 acc0 = {0,0,0,0}, acc1 = {0,0,0,0};
        for (int s = kh*2; s < kh*2 + 2; ++s){
          const int k0 = s*32;
          half8 A = *(const half8*)(wsh + DWIHF_H + (long long)n*1536 + 1024 + k0 + q*8);
          half8 B0 = ald16(wsh + CTXF_H + i16*512 + k0 + q*8);
          half8 B1 = ald16(wsh + CTXF_H + (16+i16)*512 + k0 + q*8);
          acc0 = MFMA16(A, B0, acc0);
          acc1 = MFMA16(A, B1, acc1);
        }
        #pragma unroll
        for (int r = 0; r < 4; ++r){
          sm.g.red[wv][0][q*4+r][i16] = acc0[r];
          sm.g.red[wv][1][q*4+r][i16] = acc1[r];
        }
        __syncthreads();
        if (tid < 256){
          const int uu8 = tid >> 5, b = tid & 31;
          const int j2 = uu8 >> 2, uu = uu8 & 3;
          const int bt = b >> 4, c = b & 15;
          const int unit = u0 + j2*4 + uu;
          float g4[4];
          #pragma unroll
          for (int g = 0; g < 4; ++g){
            const int tr = g*4 + uu;
            const int ng = g*1024 + unit;
            float v = 0.f;
            #pragma unroll
            for (int k = 0; k < 8; ++k) v += sm.g.red[j2 + 2*k][bt][tr][c];
            g4[g] = v + aldf(ws + DPART_F + (long long)b*4096 + ng)
                  + P.dbih[ng] + P.dbhh[ng];
          }
          const long long idx = (long long)b*1024 + unit;
          float c2 = sigf(g4[1])*ws[DC_F + idx] + sigf(g4[0])*tanhfast(g4[2]);
          ws[DC_F + idx] = c2;
          asth(wsh + DHF_H + idx, sigf(g4[3])*tanhfast(c2));
        }
      }
    }
    gbar(bar, ++ep, false);

    // ---------- PHASE B ----------
    if (bid < 32){
      // attention: pq, energies, softmax, ctx, aw/awc, alignments
      if (t < 400){
        const int b = bid;
        const int len = P.memlen[b];
        if (tid < 256){
          union { unsigned long long u; h16 h[4]; } hu;
          hu.u = aldu64(wsh + AHF_H + (long long)cur*32768 + b*1024 + tid*4);
          #pragma unroll
          for (int j = 0; j < 4; ++j) sm.row.ah[tid*4+j] = (float)hu.h[j];
        }
        if (tid < 128) sm.row.vv[tid] = P.vw[tid];
        __syncthreads();
        {
          // pq from f16 qw: 1024 threads = 8 K-eighths x 128 rows
          const int a = tid & 127, kh8 = tid >> 7;
          const h16* qr = wsh + QWF_H + (long long)a*1024 + kh8*128;
          const float* ahs = &sm.row.ah[kh8*128];
          float acc = 0.f;
          for (int k = 0; k < 128; k += 8){
            half8 wq = *(const half8*)(qr + k);
            acc += (float)wq[0]*ahs[k]   + (float)wq[1]*ahs[k+1]
                 + (float)wq[2]*ahs[k+2] + (float)wq[3]*ahs[k+3]
                 + (float)wq[4]*ahs[k+4] + (float)wq[5]*ahs[k+5]
                 + (float)wq[6]*ahs[k+6] + (float)wq[7]*ahs[k+7];
          }
          sm.row.pqp[kh8][a] = acc;
        }
        __syncthreads();
        if (tid < 128){
          float pqv = 0.f;
          #pragma unroll
          for (int k = 0; k < 8; ++k) pqv += sm.row.pqp[k][tid];
          sm.row.pq[tid] = pqv;
        }
        __syncthreads();
        // energies: one thread per t
        {
          const int tt = tid;
          if (tt < 384){
            float acc;
            if (tt < len){
              acc = 0.f;
              const unsigned long long* plp = (const unsigned long long*)
                  (wsh + PLB_H + ((long long)b*384 + tt)*128);
              for (int a0 = 0; a0 < 32; ++a0){
                union { unsigned long long u; h16 h[4]; } hu;
                hu.u = __hip_atomic_load(plp + a0, __ATOMIC_RELAXED, __HIP_MEMORY_SCOPE_AGENT);
                #pragma unroll
                for (int j = 0; j < 4; ++j)
                  acc += sm.row.vv[a0*4+j]*tanhfast(sm.row.pq[a0*4+j] + (float)hu.h[j]);
              }
            } else acc = NEGV;
            sm.row.e[tt] = acc;
          }
        }
        __syncthreads();
        float m = NEGV;
        for (int tt = tid; tt < 384; tt += 1024) m = fmaxf(m, sm.row.e[tt]);
        for (int o = 32; o; o >>= 1) m = fmaxf(m, __shfl_xor(m, o, 64));
        if ((tid & 63) == 0) sm.row.red[tid >> 6] = m;
        __syncthreads();
        float mx = sm.row.red[0];
        #pragma unroll
        for (int w = 1; w < 16; ++w) mx = fmaxf(mx, sm.row.red[w]);
        float s = 0.f;
        for (int tt = tid; tt < 384; tt += 1024){
          float wvv = (tt < len) ? __expf(sm.row.e[tt] - mx) : 0.f;
          sm.row.w[tt] = wvv; s += wvv;
        }
        for (int o = 32; o; o >>= 1) s += __shfl_xor(s, o, 64);
        if ((tid & 63) == 0) sm.row.red[16 + (tid >> 6)] = s;
        __syncthreads();
        float ssum = sm.row.red[16];
        #pragma unroll
        for (int w = 1; w < 16; ++w) ssum += sm.row.red[16+w];
        const float inv = 1.f/ssum;
        for (int tt = tid; tt < 384; tt += 1024){
          float wvv = sm.row.w[tt]*inv;
          sm.row.w[tt] = wvv;
          astf(ws + AW_F + b*384 + tt, wvv);
          float oldc = aldf(ws + AWC_F + b*384 + tt);
          astf(ws + AWC_F + b*384 + tt, oldc + wvv);
          P.out[ALIGN0 + ((long long)b*400 + t)*384 + tt] = wvv;
        }
        __syncthreads();
        // ctx from f16 memory: 1024 threads = 4 row-groups x 256 cols
        {
          const int col = tid & 255, rg = tid >> 8;
          const unsigned* mrow = (const unsigned*)(wsh + MEMF_H) + (long long)b*98304;
          float acc0 = 0.f, acc1 = 0.f;
          for (int t4 = rg*24; t4 < rg*24 + 24; ++t4){
            float4 w4 = *reinterpret_cast<const float4*>(&sm.row.w[t4*4]);
            const unsigned* m0 = mrow + t4*1024 + col;
            unsigned v0 = m0[0], v1 = m0[256], v2 = m0[512], v3 = m0[768];
            union { unsigned u; h16 h[2]; } d0, d1, d2, d3;
            d0.u = v0; d1.u = v1; d2.u = v2; d3.u = v3;
            acc0 += w4.x*(float)d0.h[0] + w4.y*(float)d1.h[0]
                  + w4.z*(float)d2.h[0] + w4.w*(float)d3.h[0];
            acc1 += w4.x*(float)d0.h[1] + w4.y*(float)d1.h[1]
                  + w4.z*(float)d2.h[1] + w4.w*(float)d3.h[1];
          }
          sm.row.ctxred[rg][col][0] = acc0;
          sm.row.ctxred[rg][col][1] = acc1;
          __syncthreads();
          if (tid < 256){
            union { h16 h[2]; unsigned u; } cv;
            cv.h[0] = (h16)(sm.row.ctxred[0][tid][0] + sm.row.ctxred[1][tid][0]
                          + sm.row.ctxred[2][tid][0] + sm.row.ctxred[3][tid][0]);
            cv.h[1] = (h16)(sm.row.ctxred[0][tid][1] + sm.row.ctxred[1][tid][1]
                          + sm.row.ctxred[2][tid][1] + sm.row.ctxred[3][tid][1]);
            astu32((unsigned*)(wsh + CTXF_H) + b*256 + tid, cv.u);
          }
        }
      }
    } else if (bid < 288){
      // dec-LSTM ah/dh partial (K=2048): 16 rows/block.
      // 16 waves = 8 K-groups x 2 batch-halves; 8 K-steps x 1 MFMA each.
      if (t < 400){
        const int n0 = (bid-32)*16;
        const int n = n0 + i16;
        const int w8 = wv & 7, bt = wv >> 3;
        const int row0 = bt*16 + i16;
        f32x4 acc = {0,0,0,0};
        const long long curO = (long long)cur*32768;
        for (int s = w8*8; s < w8*8 + 8; ++s){
          const int k0 = s*32;
          const h16* pA = (k0 < 1024) ? wsh + DWIHF_H + (long long)n*1536 + k0 + q*8
                                      : wsh + DWHHF_H + (long long)n*1024 + (k0-1024) + q*8;
          half8 A = *(const half8*)pA;
          half8 B;
          if (k0 < 1024) B = ald16(wsh + AHF_H + curO + (long long)row0*1024 + k0 + q*8);
          else           B = ald16(wsh + DHF_H + (long long)row0*1024 + (k0-1024) + q*8);
          acc = MFMA16(A, B, acc);
        }
        #pragma unroll
        for (int r = 0; r < 4; ++r) sm.g.red[w8][bt][q*4+r][i16] = acc[r];
        __syncthreads();
        if (tid < 256){
          const int r16 = tid & 15, c = tid >> 4;
          #pragma unroll
          for (int bt2 = 0; bt2 < 2; ++bt2){
            float v = 0.f;
            #pragma unroll
            for (int w = 0; w < 8; ++w) v += sm.g.red[w][bt2][r16][c];
            astf(ws + DPART_F + (long long)(bt2*16 + c)*4096 + n0 + r16, v);
          }
        }
      }
    } else if (bid < 320){
      // mel + gate projections for step t-1; proj weights from f16 copy
      if (t >= 1){
        const int b = bid - 288;
        for (int i = tid; i < 384; i += 1024){
          union { unsigned long long u; h16 h[4]; } hu;
          hu.u = (i < 256) ? aldu64(wsh + DHF_H + b*1024 + i*4)
                           : aldu64(wsh + CTXF_H + b*512 + (i-256)*4);
          #pragma unroll
          for (int j = 0; j < 4; ++j) sm.mel.hc[i*4+j] = (float)hu.h[j];
        }
        __syncthreads();
        if (tid < 640){
          const int r = tid >> 3, h8 = tid & 7;      // 80 rows x 8 K-eighths
          const h16* pr = wsh + PWF_H + (long long)r*1536 + h8*192;
          const float* hcp = &sm.mel.hc[h8*192];
          float acc = 0.f;
          for (int k = 0; k < 192; k += 8){
            half8 wq = *(const half8*)(pr + k);
            acc += (float)wq[0]*hcp[k]   + (float)wq[1]*hcp[k+1]
                 + (float)wq[2]*hcp[k+2] + (float)wq[3]*hcp[k+3]
                 + (float)wq[4]*hcp[k+4] + (float)wq[5]*hcp[k+5]
                 + (float)wq[6]*hcp[k+6] + (float)wq[7]*hcp[k+7];
          }
          sm.mel.mp[r][h8] = acc;
        } else if (tid >= 768 && tid < 832){
          const int l = tid - 768;                   // wave 12, full wave
          const float* gp  = P.gw + l*24;
          const float* hcp = &sm.mel.hc[l*24];
          float acc = 0.f;
          #pragma unroll
          for (int k = 0; k < 24; ++k) acc += gp[k]*hcp[k];
          for (int o = 32; o; o >>= 1) acc += __shfl_xor(acc, o, 64);
          if (l == 0) sm.mel.gacc = acc;
        }
        __syncthreads();
        if (tid < 80){
          float v = P.pb[tid];
          #pragma unroll
          for (int k = 0; k < 8; ++k) v += sm.mel.mp[tid][k];
          P.out[((long long)b*80 + tid)*400 + (t-1)] = v;
        }
        if (tid == 80)
          P.out[GATE0 + (long long)b*400 + (t-1)] = sm.mel.gacc + P.gb[0];
      }
    }
    gbar(bar, ++ep, false);
  }
}

extern "C" void kernel_launch(void* const* d_in, const int* in_sizes, int n_in,
                              void* d_out, int out_size, void* d_ws, size_t ws_size,
                              hipStream_t stream) {
  (void)in_sizes; (void)n_in; (void)out_size; (void)ws_size;
  Params p;
  p.memory = (const float*)d_in[0];
  p.dec_in = (const float*)d_in[1];
  p.memlen = (const int*)d_in[2];
  p.w1   = (const float*)d_in[3];
  p.w2   = (const float*)d_in[4];
  p.awih = (const float*)d_in[5];
  p.awhh = (const float*)d_in[6];
  p.abih = (const float*)d_in[7];
  p.abhh = (const float*)d_in[8];
  p.qw   = (const float*)d_in[9];
  p.mw   = (const float*)d_in[10];
  p.vw   = (const float*)d_in[11];
  p.lcw  = (const float*)d_in[12];
  p.ldw  = (const float*)d_in[13];
  p.dwih = (const float*)d_in[14];
  p.dwhh = (const float*)d_in[15];
  p.dbih = (const float*)d_in[16];
  p.dbhh = (const float*)d_in[17];
  p.pw   = (const float*)d_in[18];
  p.pb   = (const float*)d_in[19];
  p.gw   = (const float*)d_in[20];
  p.gb   = (const float*)d_in[21];
  p.out  = (float*)d_out;
  p.ws   = (float*)d_ws;

  hipLaunchKernelGGL(init_kernel, dim3(1), dim3(512), 0, stream, p.ws);
  hipLaunchKernelGGL(decoder_kernel, dim3(512), dim3(1024), 0, stream, p);
}

// Round 8
// 44176.556 us; speedup vs baseline: 1.0214x; 1.0214x over previous
//
#include <hip/hip_runtime.h>

typedef _Float16 h16;
typedef _Float16 half8 __attribute__((ext_vector_type(8)));
typedef float f32x4 __attribute__((ext_vector_type(4)));

#define NEGV -1000000000.0f
#define MFMA16(a,b,c) __builtin_amdgcn_mfma_f32_16x16x32_f16(a,b,c,0,0,0)

struct Params {
  const float *memory, *dec_in; const int *memlen;
  const float *w1, *w2;
  const float *awih, *awhh, *abih, *abhh;
  const float *qw, *mw, *vw, *lcw, *ldw;
  const float *dwih, *dwhh, *dbih, *dbhh;
  const float *pw, *pb, *gw, *gb;
  float *out, *ws;
};

// ---- ws layout ----
// f16 arrays: offsets in HALFS
constexpr long long XALLF_H = 0;          // 400*32*256  xallf[t][b][256]
constexpr long long PMH_H   = 3276800;    // 32*128*384  pm[b][a][t]
constexpr long long PLB_H   = 4849664;    // 32*384*128  plb[b][t][a]
constexpr long long AWIHF_H = 6422528;    // 4096*768
constexpr long long AWHHF_H = 9568256;    // 4096*1024
constexpr long long DWIHF_H = 13762560;   // 4096*1536
constexpr long long DWHHF_H = 20054016;   // 4096*1024
constexpr long long LCWF_H  = 24248320;   // 32*64 (padded conv wts, f-major)
constexpr long long LDWF_H  = 24250368;   // 128*32 (a-major)
constexpr long long AHF_H   = 24254464;   // 2 * 32*1024 (double buffered)
constexpr long long DHF_H   = 24320000;   // 32*1024
constexpr long long CTXF_H  = 24352768;   // 32*512
// f16 read-only copies of per-step-streamed fp32 tensors (bytes halved):
constexpr long long MEMF_H  = 24812544;   // 32*384*512 memory (f16)
constexpr long long PWF_H   = 31104000;   // 80*1536 proj weights (f16)
constexpr long long QWF_H   = 31226880;   // 128*1024 query weights (f16)
// fp32 arrays: offsets in FLOATS
constexpr long long ZERO_F0 = 12127232;   // zero region start (covers AHF..DPART)
constexpr long long AC_F    = 12184576;   // 32*1024
constexpr long long DC_F    = 12217344;   // 32*1024
constexpr long long AW_F    = 12250112;   // 32*384
constexpr long long AWC_F   = 12262400;   // 32*384
constexpr long long DPART_F = 12274688;   // 32*4096
constexpr long long BAR_F   = 12405760;   // 512 uints
constexpr int  ZERO_LEN = 278528;
constexpr unsigned NBLK = 512;
// out layout
constexpr long long GATE0  = 1024000;
constexpr long long ALIGN0 = 1036800;

union SMem {
  float pmstage[12][512];                                     // 24.6 KB
  struct { float x[5][80]; float l1[5][256]; } pre;
  struct { float red[16][2][16][17]; } g;                     // 34.8 KB (16 waves)
  struct { float awseg[2][128]; h16 im2[96][72]; h16 locT[96][32];
           unsigned p16[96][64]; } ploc;                      // 45.6 KB (max)
  struct { float ah[1024]; float pq[128]; float pqp[8][128]; float vv[128];
           float e[384]; float w[384]; float red[32];
           float ctxred[4][256][2]; } row;                    // ~20 KB
  struct { float hc[1536]; float mp[80][8]; float gacc; } mel;
};

__device__ __forceinline__ float sigf(float x){ return 1.0f/(1.0f+__expf(-x)); }
__device__ __forceinline__ float tanhfast(float x){ float e2 = __expf(2.0f*x); return 1.0f - 2.0f/(e2+1.0f); }

// ---- agent-scope (cross-XCD coherent, cache-bypassing) accessors ----
__device__ __forceinline__ float aldf(const float* p){
  return __hip_atomic_load(p, __ATOMIC_RELAXED, __HIP_MEMORY_SCOPE_AGENT);
}
__device__ __forceinline__ void astf(float* p, float v){
  __hip_atomic_store(p, v, __ATOMIC_RELAXED, __HIP_MEMORY_SCOPE_AGENT);
}
__device__ __forceinline__ unsigned long long aldu64(const h16* p){
  return __hip_atomic_load((const unsigned long long*)p, __ATOMIC_RELAXED, __HIP_MEMORY_SCOPE_AGENT);
}
__device__ __forceinline__ half8 ald16(const h16* p){
  union { unsigned long long q[2]; half8 v; } u;
  u.q[0] = __hip_atomic_load((const unsigned long long*)p,     __ATOMIC_RELAXED, __HIP_MEMORY_SCOPE_AGENT);
  u.q[1] = __hip_atomic_load(((const unsigned long long*)p)+1, __ATOMIC_RELAXED, __HIP_MEMORY_SCOPE_AGENT);
  return u.v;
}
__device__ __forceinline__ void asth(h16* p, float v){
  union { h16 h; unsigned short s; } u; u.h = (h16)v;
  __hip_atomic_store((unsigned short*)p, u.s, __ATOMIC_RELAXED, __HIP_MEMORY_SCOPE_AGENT);
}
__device__ __forceinline__ void astu32(unsigned* p, unsigned v){
  __hip_atomic_store(p, v, __ATOMIC_RELAXED, __HIP_MEMORY_SCOPE_AGENT);
}

// software grid barrier; full=true adds release/acquire cache maintenance
__device__ __forceinline__ void gbar(unsigned* cnts, unsigned ep, bool full){
  __syncthreads();
  if (threadIdx.x == 0){
    if (full) __threadfence();
    __hip_atomic_fetch_add(&cnts[(blockIdx.x & 7)*64], 1u, __ATOMIC_RELEASE, __HIP_MEMORY_SCOPE_AGENT);
    const unsigned tgt = ep*NBLK;
    for (;;){
      unsigned s = 0;
      #pragma unroll
      for (int i = 0; i < 8; ++i)
        s += __hip_atomic_load(&cnts[i*64], __ATOMIC_RELAXED, __HIP_MEMORY_SCOPE_AGENT);
      if (s >= tgt) break;
      __builtin_amdgcn_s_sleep(4);
    }
    if (full) __threadfence();
  }
  __syncthreads();
}

__global__ void init_kernel(float* ws){
  unsigned* c = (unsigned*)(ws + BAR_F);
  if (threadIdx.x < 512) c[threadIdx.x] = 0u;
}

// 1024 threads/block (16 waves), 32 waves/CU. A-tiles SHARED across both
// batch-halves within each wave (2 MFMA per weight load) — the round-7
// 8Kx2batch split doubled weight fetch (FETCH 1.9e7->3.2e7 KB); this keeps
// the 99% occupancy while restoring single-fetch weights.
__global__ __launch_bounds__(1024, 8)
void decoder_kernel(Params P){
  __shared__ SMem sm;
  const int tid = threadIdx.x;
  const int bid = blockIdx.x;
  float* ws = P.ws;
  h16*   wsh = (h16*)ws;
  unsigned* bar = (unsigned*)(ws + BAR_F);
  unsigned ep = 0;

  const int lane = tid & 63, wv = tid >> 6;          // wv in 0..15
  const int i16 = lane & 15, q = lane >> 4;

  // ============== PROLOGUE ==============
  {
    const long long gtid = (long long)bid*1024 + tid;
    const long long GS = 524288;
    for (long long i = gtid; i < ZERO_LEN; i += GS) ws[ZERO_F0 + i] = 0.f;
    for (long long i = gtid; i < 3145728; i += GS) wsh[AWIHF_H+i] = (h16)P.awih[i];
    for (long long i = gtid; i < 4194304; i += GS) wsh[AWHHF_H+i] = (h16)P.awhh[i];
    for (long long i = gtid; i < 6291456; i += GS) wsh[DWIHF_H+i] = (h16)P.dwih[i];
    for (long long i = gtid; i < 4194304; i += GS) wsh[DWHHF_H+i] = (h16)P.dwhh[i];
    for (long long i = gtid; i < 6291456; i += GS) wsh[MEMF_H+i] = (h16)P.memory[i];
    for (long long i = gtid; i < 122880; i += GS) wsh[PWF_H+i] = (h16)P.pw[i];
    for (long long i = gtid; i < 131072; i += GS) wsh[QWF_H+i] = (h16)P.qw[i];
    for (long long i = gtid; i < 2048; i += GS){
      int f = (int)(i >> 6), kk = (int)(i & 63), ch = kk >> 5, k = kk & 31;
      wsh[LCWF_H+i] = (k < 31) ? (h16)P.lcw[f*62 + ch*31 + k] : (h16)0.f;
    }
    for (long long i = gtid; i < 4096; i += GS) wsh[LDWF_H+i] = (h16)P.ldw[i];
  }
  // processed_memory -> PMH (f16)
  {
    const int b = bid >> 4, part = bid & 15;
    for (int sub = 0; sub < 2; ++sub){
      const int t0 = part*24 + sub*12;
      __syncthreads();
      for (int i = tid; i < 1536; i += 1024){
        int row = i >> 7, c4 = (i & 127) << 2;
        *reinterpret_cast<float4*>(&sm.pmstage[row][c4]) =
          *reinterpret_cast<const float4*>(P.memory + ((long long)(b*384 + t0 + row))*512 + c4);
      }
      __syncthreads();
      if (tid < 512){
        const int a = tid & 127, th = tid >> 7;
        float acc[3] = {0,0,0};
        const float* mwr = P.mw + (long long)a*512;
        for (int e = 0; e < 512; ++e){
          float wvv = mwr[e];
          #pragma unroll
          for (int jj = 0; jj < 3; ++jj) acc[jj] += wvv*sm.pmstage[th*3+jj][e];
        }
        #pragma unroll
        for (int jj = 0; jj < 3; ++jj)
          wsh[PMH_H + ((long long)b*128 + a)*384 + t0 + th*3 + jj] = (h16)acc[jj];
      }
    }
  }
  // prenet -> XALLF (f16)
  {
    for (int batch = 0; batch < 5; ++batch){
      const int pbase = bid*25 + batch*5;
      __syncthreads();
      for (int i = tid; i < 400; i += 1024){
        int j = i/80, m = i%80;
        int p = pbase + j; int tq = p >> 5, bb = p & 31;
        float v = 0.f;
        if (tq > 0) v = P.dec_in[((long long)bb*80 + m)*400 + (tq-1)];
        sm.pre.x[j][m] = v;
      }
      __syncthreads();
      {
        float acc[5] = {0,0,0,0,0};
        if (tid < 256){
          const float* w1r = P.w1 + (long long)tid*80;
          for (int m = 0; m < 80; ++m){
            float wvv = w1r[m];
            #pragma unroll
            for (int j = 0; j < 5; ++j) acc[j] += wvv*sm.pre.x[j][m];
          }
        }
        __syncthreads();
        if (tid < 256){
          #pragma unroll
          for (int j = 0; j < 5; ++j) sm.pre.l1[j][tid] = fmaxf(acc[j], 0.f);
        }
      }
      __syncthreads();
      if (tid < 256){
        float acc[5] = {0,0,0,0,0};
        const float* w2r = P.w2 + (long long)tid*256;
        for (int pp = 0; pp < 256; ++pp){
          float wvv = w2r[pp];
          #pragma unroll
          for (int j = 0; j < 5; ++j) acc[j] += wvv*sm.pre.l1[j][pp];
        }
        #pragma unroll
        for (int j = 0; j < 5; ++j){
          int p = pbase + j; int tq = p >> 5, bb = p & 31;
          wsh[XALLF_H + ((long long)tq*32 + bb)*256 + tid] = (h16)fmaxf(acc[j], 0.f);
        }
      }
    }
  }
  gbar(bar, ++ep, true);   // full fence once: weights/PMH/XALLF now visible + cached

  // ============== MAIN LOOP ==============
  for (int t = 0; t <= 400; ++t){
    const int cur = t & 1, prv = (t+1) & 1;

    // ---------- PHASE A ----------
    if (bid < 256){
      // att-LSTM: 4 units/block. 16 waves split 56 K-steps (3 or 4 each);
      // each step: ONE A load, TWO MFMAs (both batch halves).
      if (t < 400){
        const int u0 = bid*4;
        const int n = ((i16 >> 2)*1024) + u0 + (i16 & 3);   // gate-gathered row
        f32x4 acc0 = {0,0,0,0}, acc1 = {0,0,0,0};
        const long long prvO = (long long)prv*32768;
        const int s0 = (wv*56) >> 4, s1 = ((wv+1)*56) >> 4;
        for (int s = s0; s < s1; ++s){
          const int k0 = s*32;
          const h16* pA = (k0 < 768) ? wsh + AWIHF_H + (long long)n*768 + k0 + q*8
                                     : wsh + AWHHF_H + (long long)n*1024 + (k0-768) + q*8;
          half8 A = *(const half8*)pA;
          half8 B0, B1;
          if (k0 < 256){
            B0 = *(const half8*)(wsh + XALLF_H + ((long long)t*32 + i16)*256 + k0 + q*8);
            B1 = *(const half8*)(wsh + XALLF_H + ((long long)t*32 + 16 + i16)*256 + k0 + q*8);
          } else if (k0 < 768){
            B0 = ald16(wsh + CTXF_H + i16*512 + (k0-256) + q*8);
            B1 = ald16(wsh + CTXF_H + (16+i16)*512 + (k0-256) + q*8);
          } else {
            B0 = ald16(wsh + AHF_H + prvO + i16*1024 + (k0-768) + q*8);
            B1 = ald16(wsh + AHF_H + prvO + (16+i16)*1024 + (k0-768) + q*8);
          }
          acc0 = MFMA16(A, B0, acc0);
          acc1 = MFMA16(A, B1, acc1);
        }
        #pragma unroll
        for (int r = 0; r < 4; ++r){
          sm.g.red[wv][0][q*4+r][i16] = acc0[r];
          sm.g.red[wv][1][q*4+r][i16] = acc1[r];
        }
        __syncthreads();
        if (tid < 128){
          const int uu = tid >> 5, b = tid & 31;
          const int bt2 = b >> 4, c = b & 15;
          float g4[4];
          #pragma unroll
          for (int g = 0; g < 4; ++g){
            const int tr = g*4 + uu;
            float v = 0.f;
            #pragma unroll
            for (int w = 0; w < 16; ++w) v += sm.g.red[w][bt2][tr][c];
            const int ng = g*1024 + u0 + uu;
            g4[g] = v + P.abih[ng] + P.abhh[ng];
          }
          const long long idx = (long long)b*1024 + u0 + uu;
          float c2 = sigf(g4[1])*ws[AC_F + idx] + sigf(g4[0])*tanhfast(g4[2]);
          ws[AC_F + idx] = c2;
          asth(wsh + AHF_H + (long long)cur*32768 + idx, sigf(g4[3])*tanhfast(c2));
        }
      }
    } else if (bid < 384){
      // loc conv + dense via MFMA -> plb f16 [b][t][a]
      if (t < 400){
        const int pb = bid - 256, b = pb >> 2, tbase = (pb & 3)*96;
        for (int i = tid; i < 252; i += 1024){
          int ch = i / 126, ix = i % 126;
          int pos = tbase - 15 + ix;
          float v = 0.f;
          if (pos >= 0 && pos < 384)
            v = aldf(ws + (ch ? AWC_F : AW_F) + b*384 + pos);
          sm.ploc.awseg[ch][ix] = v;
        }
        __syncthreads();
        for (int i = tid; i < 96*64; i += 1024){
          int tt = i >> 6, kk = i & 63, ch = kk >> 5, k = kk & 31;
          sm.ploc.im2[tt][kk] = (k < 31) ? (h16)sm.ploc.awseg[ch][tt + k] : (h16)0.f;
        }
        __syncthreads();
        // conv: 12 tiles over 16 waves (4 idle)
        {
          int tile = wv;
          if (tile < 12){
            int tT = tile % 6, tF = tile / 6;
            f32x4 a = {0,0,0,0};
            #pragma unroll
            for (int ks = 0; ks < 2; ++ks){
              half8 A = *(const half8*)&sm.ploc.im2[tT*16 + i16][ks*32 + q*8];
              half8 B = *(const half8*)(wsh + LCWF_H + (tF*16 + i16)*64 + ks*32 + q*8);
              a = MFMA16(A, B, a);
            }
            #pragma unroll
            for (int r = 0; r < 4; ++r)
              sm.ploc.locT[tT*16 + q*4 + r][tF*16 + i16] = (h16)a[r];
          }
        }
        __syncthreads();
        // dense: 48 tiles over 16 waves = 3/wave
        unsigned short* s16 = (unsigned short*)&sm.ploc.p16[0][0];
        #pragma unroll
        for (int p = 0; p < 3; ++p){
          int tile = wv + p*16;
          int tT = tile % 6, tA = tile / 6;
          half8 A = *(const half8*)&sm.ploc.locT[tT*16 + i16][q*8];
          half8 B = *(const half8*)(wsh + LDWF_H + (tA*16 + i16)*32 + q*8);
          f32x4 a = {0,0,0,0};
          a = MFMA16(A, B, a);
          int aa = tA*16 + i16;
          union { unsigned long long u; h16 h[4]; } pmu;
          pmu.u = *(const unsigned long long*)
              (wsh + PMH_H + ((long long)b*128 + aa)*384 + tbase + tT*16 + q*4);
          #pragma unroll
          for (int r = 0; r < 4; ++r){
            union { h16 h; unsigned short s; } cv;
            cv.h = (h16)(a[r] + (float)pmu.h[r]);
            s16[(tT*16 + q*4 + r)*128 + aa] = cv.s;
          }
        }
        __syncthreads();
        unsigned* plbu = (unsigned*)(wsh + PLB_H);
        for (int i = tid; i < 96*64; i += 1024){
          int tt = i >> 6, a2 = i & 63;
          astu32(plbu + ((long long)b*384 + tbase + tt)*64 + a2, sm.ploc.p16[tt][a2]);
        }
      }
    } else {
      // dec-LSTM ctx-part (K=512) + cell for step t-1: 8 units/block.
      // 16 waves = 2 unit-quads x 8 K-eighths; A shared across B0/B1.
      if (t >= 1){
        const int u0 = (bid-384)*8;
        const int jt = wv & 1, kh = wv >> 1;          // kh in 0..7
        const int n = ((i16 >> 2)*1024) + u0 + jt*4 + (i16 & 3);
        f32x4 acc0 = {0,0,0,0}, acc1 = {0,0,0,0};
        for (int s = kh*2; s < kh*2 + 2; ++s){
          const int k0 = s*32;
          half8 A = *(const half8*)(wsh + DWIHF_H + (long long)n*1536 + 1024 + k0 + q*8);
          half8 B0 = ald16(wsh + CTXF_H + i16*512 + k0 + q*8);
          half8 B1 = ald16(wsh + CTXF_H + (16+i16)*512 + k0 + q*8);
          acc0 = MFMA16(A, B0, acc0);
          acc1 = MFMA16(A, B1, acc1);
        }
        #pragma unroll
        for (int r = 0; r < 4; ++r){
          sm.g.red[wv][0][q*4+r][i16] = acc0[r];
          sm.g.red[wv][1][q*4+r][i16] = acc1[r];
        }
        __syncthreads();
        if (tid < 256){
          const int uu8 = tid >> 5, b = tid & 31;
          const int j2 = uu8 >> 2, uu = uu8 & 3;
          const int bt = b >> 4, c = b & 15;
          const int unit = u0 + j2*4 + uu;
          float g4[4];
          #pragma unroll
          for (int g = 0; g < 4; ++g){
            const int tr = g*4 + uu;
            const int ng = g*1024 + unit;
            float v = 0.f;
            #pragma unroll
            for (int k = 0; k < 8; ++k) v += sm.g.red[j2 + 2*k][bt][tr][c];
            g4[g] = v + aldf(ws + DPART_F + (long long)b*4096 + ng)
                  + P.dbih[ng] + P.dbhh[ng];
          }
          const long long idx = (long long)b*1024 + unit;
          float c2 = sigf(g4[1])*ws[DC_F + idx] + sigf(g4[0])*tanhfast(g4[2]);
          ws[DC_F + idx] = c2;
          asth(wsh + DHF_H + idx, sigf(g4[3])*tanhfast(c2));
        }
      }
    }
    gbar(bar, ++ep, false);

    // ---------- PHASE B ----------
    if (bid < 32){
      // attention: pq, energies, softmax, ctx, aw/awc, alignments
      if (t < 400){
        const int b = bid;
        const int len = P.memlen[b];
        if (tid < 256){
          union { unsigned long long u; h16 h[4]; } hu;
          hu.u = aldu64(wsh + AHF_H + (long long)cur*32768 + b*1024 + tid*4);
          #pragma unroll
          for (int j = 0; j < 4; ++j) sm.row.ah[tid*4+j] = (float)hu.h[j];
        }
        if (tid < 128) sm.row.vv[tid] = P.vw[tid];
        __syncthreads();
        {
          // pq from f16 qw: 1024 threads = 8 K-eighths x 128 rows
          const int a = tid & 127, kh8 = tid >> 7;
          const h16* qr = wsh + QWF_H + (long long)a*1024 + kh8*128;
          const float* ahs = &sm.row.ah[kh8*128];
          float acc = 0.f;
          for (int k = 0; k < 128; k += 8){
            half8 wq = *(const half8*)(qr + k);
            acc += (float)wq[0]*ahs[k]   + (float)wq[1]*ahs[k+1]
                 + (float)wq[2]*ahs[k+2] + (float)wq[3]*ahs[k+3]
                 + (float)wq[4]*ahs[k+4] + (float)wq[5]*ahs[k+5]
                 + (float)wq[6]*ahs[k+6] + (float)wq[7]*ahs[k+7];
          }
          sm.row.pqp[kh8][a] = acc;
        }
        __syncthreads();
        if (tid < 128){
          float pqv = 0.f;
          #pragma unroll
          for (int k = 0; k < 8; ++k) pqv += sm.row.pqp[k][tid];
          sm.row.pq[tid] = pqv;
        }
        __syncthreads();
        // energies: one thread per t
        {
          const int tt = tid;
          if (tt < 384){
            float acc;
            if (tt < len){
              acc = 0.f;
              const unsigned long long* plp = (const unsigned long long*)
                  (wsh + PLB_H + ((long long)b*384 + tt)*128);
              for (int a0 = 0; a0 < 32; ++a0){
                union { unsigned long long u; h16 h[4]; } hu;
                hu.u = __hip_atomic_load(plp + a0, __ATOMIC_RELAXED, __HIP_MEMORY_SCOPE_AGENT);
                #pragma unroll
                for (int j = 0; j < 4; ++j)
                  acc += sm.row.vv[a0*4+j]*tanhfast(sm.row.pq[a0*4+j] + (float)hu.h[j]);
              }
            } else acc = NEGV;
            sm.row.e[tt] = acc;
          }
        }
        __syncthreads();
        float m = NEGV;
        for (int tt = tid; tt < 384; tt += 1024) m = fmaxf(m, sm.row.e[tt]);
        for (int o = 32; o; o >>= 1) m = fmaxf(m, __shfl_xor(m, o, 64));
        if ((tid & 63) == 0) sm.row.red[tid >> 6] = m;
        __syncthreads();
        float mx = sm.row.red[0];
        #pragma unroll
        for (int w = 1; w < 16; ++w) mx = fmaxf(mx, sm.row.red[w]);
        float s = 0.f;
        for (int tt = tid; tt < 384; tt += 1024){
          float wvv = (tt < len) ? __expf(sm.row.e[tt] - mx) : 0.f;
          sm.row.w[tt] = wvv; s += wvv;
        }
        for (int o = 32; o; o >>= 1) s += __shfl_xor(s, o, 64);
        if ((tid & 63) == 0) sm.row.red[16 + (tid >> 6)] = s;
        __syncthreads();
        float ssum = sm.row.red[16];
        #pragma unroll
        for (int w = 1; w < 16; ++w) ssum += sm.row.red[16+w];
        const float inv = 1.f/ssum;
        for (int tt = tid; tt < 384; tt += 1024){
          float wvv = sm.row.w[tt]*inv;
          sm.row.w[tt] = wvv;
          astf(ws + AW_F + b*384 + tt, wvv);
          float oldc = aldf(ws + AWC_F + b*384 + tt);
          astf(ws + AWC_F + b*384 + tt, oldc + wvv);
          P.out[ALIGN0 + ((long long)b*400 + t)*384 + tt] = wvv;
        }
        __syncthreads();
        // ctx from f16 memory: 1024 threads = 4 row-groups x 256 cols
        {
          const int col = tid & 255, rg = tid >> 8;
          const unsigned* mrow = (const unsigned*)(wsh + MEMF_H) + (long long)b*98304;
          float acc0 = 0.f, acc1 = 0.f;
          for (int t4 = rg*24; t4 < rg*24 + 24; ++t4){
            float4 w4 = *reinterpret_cast<const float4*>(&sm.row.w[t4*4]);
            const unsigned* m0 = mrow + t4*1024 + col;
            unsigned v0 = m0[0], v1 = m0[256], v2 = m0[512], v3 = m0[768];
            union { unsigned u; h16 h[2]; } d0, d1, d2, d3;
            d0.u = v0; d1.u = v1; d2.u = v2; d3.u = v3;
            acc0 += w4.x*(float)d0.h[0] + w4.y*(float)d1.h[0]
                  + w4.z*(float)d2.h[0] + w4.w*(float)d3.h[0];
            acc1 += w4.x*(float)d0.h[1] + w4.y*(float)d1.h[1]
                  + w4.z*(float)d2.h[1] + w4.w*(float)d3.h[1];
          }
          sm.row.ctxred[rg][col][0] = acc0;
          sm.row.ctxred[rg][col][1] = acc1;
          __syncthreads();
          if (tid < 256){
            union { h16 h[2]; unsigned u; } cv;
            cv.h[0] = (h16)(sm.row.ctxred[0][tid][0] + sm.row.ctxred[1][tid][0]
                          + sm.row.ctxred[2][tid][0] + sm.row.ctxred[3][tid][0]);
            cv.h[1] = (h16)(sm.row.ctxred[0][tid][1] + sm.row.ctxred[1][tid][1]
                          + sm.row.ctxred[2][tid][1] + sm.row.ctxred[3][tid][1]);
            astu32((unsigned*)(wsh + CTXF_H) + b*256 + tid, cv.u);
          }
        }
      }
    } else if (bid < 288){
      // dec-LSTM ah/dh partial (K=2048): 16 rows/block.
      // 16 waves split 64 K-steps (4 each); A shared, 2 MFMA per step.
      if (t < 400){
        const int n0 = (bid-32)*16;
        const int n = n0 + i16;
        f32x4 acc0 = {0,0,0,0}, acc1 = {0,0,0,0};
        const long long curO = (long long)cur*32768;
        for (int s = wv*4; s < wv*4 + 4; ++s){
          const int k0 = s*32;
          const h16* pA = (k0 < 1024) ? wsh + DWIHF_H + (long long)n*1536 + k0 + q*8
                                      : wsh + DWHHF_H + (long long)n*1024 + (k0-1024) + q*8;
          half8 A = *(const half8*)pA;
          half8 B0, B1;
          if (k0 < 1024){
            B0 = ald16(wsh + AHF_H + curO + i16*1024 + k0 + q*8);
            B1 = ald16(wsh + AHF_H + curO + (16+i16)*1024 + k0 + q*8);
          } else {
            B0 = ald16(wsh + DHF_H + i16*1024 + (k0-1024) + q*8);
            B1 = ald16(wsh + DHF_H + (16+i16)*1024 + (k0-1024) + q*8);
          }
          acc0 = MFMA16(A, B0, acc0);
          acc1 = MFMA16(A, B1, acc1);
        }
        #pragma unroll
        for (int r = 0; r < 4; ++r){
          sm.g.red[wv][0][q*4+r][i16] = acc0[r];
          sm.g.red[wv][1][q*4+r][i16] = acc1[r];
        }
        __syncthreads();
        if (tid < 256){
          const int r16 = tid & 15, c = tid >> 4;
          #pragma unroll
          for (int bt2 = 0; bt2 < 2; ++bt2){
            float v = 0.f;
            #pragma unroll
            for (int w = 0; w < 16; ++w) v += sm.g.red[w][bt2][r16][c];
            astf(ws + DPART_F + (long long)(bt2*16 + c)*4096 + n0 + r16, v);
          }
        }
      }
    } else if (bid < 320){
      // mel + gate projections for step t-1; proj weights from f16 copy
      if (t >= 1){
        const int b = bid - 288;
        for (int i = tid; i < 384; i += 1024){
          union { unsigned long long u; h16 h[4]; } hu;
          hu.u = (i < 256) ? aldu64(wsh + DHF_H + b*1024 + i*4)
                           : aldu64(wsh + CTXF_H + b*512 + (i-256)*4);
          #pragma unroll
          for (int j = 0; j < 4; ++j) sm.mel.hc[i*4+j] = (float)hu.h[j];
        }
        __syncthreads();
        if (tid < 640){
          const int r = tid >> 3, h8 = tid & 7;      // 80 rows x 8 K-eighths
          const h16* pr = wsh + PWF_H + (long long)r*1536 + h8*192;
          const float* hcp = &sm.mel.hc[h8*192];
          float acc = 0.f;
          for (int k = 0; k < 192; k += 8){
            half8 wq = *(const half8*)(pr + k);
            acc += (float)wq[0]*hcp[k]   + (float)wq[1]*hcp[k+1]
                 + (float)wq[2]*hcp[k+2] + (float)wq[3]*hcp[k+3]
                 + (float)wq[4]*hcp[k+4] + (float)wq[5]*hcp[k+5]
                 + (float)wq[6]*hcp[k+6] + (float)wq[7]*hcp[k+7];
          }
          sm.mel.mp[r][h8] = acc;
        } else if (tid >= 768 && tid < 832){
          const int l = tid - 768;                   // wave 12, full wave
          const float* gp  = P.gw + l*24;
          const float* hcp = &sm.mel.hc[l*24];
          float acc = 0.f;
          #pragma unroll
          for (int k = 0; k < 24; ++k) acc += gp[k]*hcp[k];
          for (int o = 32; o; o >>= 1) acc += __shfl_xor(acc, o, 64);
          if (l == 0) sm.mel.gacc = acc;
        }
        __syncthreads();
        if (tid < 80){
          float v = P.pb[tid];
          #pragma unroll
          for (int k = 0; k < 8; ++k) v += sm.mel.mp[tid][k];
          P.out[((long long)b*80 + tid)*400 + (t-1)] = v;
        }
        if (tid == 80)
          P.out[GATE0 + (long long)b*400 + (t-1)] = sm.mel.gacc + P.gb[0];
      }
    }
    gbar(bar, ++ep, false);
  }
}

extern "C" void kernel_launch(void* const* d_in, const int* in_sizes, int n_in,
                              void* d_out, int out_size, void* d_ws, size_t ws_size,
                              hipStream_t stream) {
  (void)in_sizes; (void)n_in; (void)out_size; (void)ws_size;
  Params p;
  p.memory = (const float*)d_in[0];
  p.dec_in = (const float*)d_in[1];
  p.memlen = (const int*)d_in[2];
  p.w1   = (const float*)d_in[3];
  p.w2   = (const float*)d_in[4];
  p.awih = (const float*)d_in[5];
  p.awhh = (const float*)d_in[6];
  p.abih = (const float*)d_in[7];
  p.abhh = (const float*)d_in[8];
  p.qw   = (const float*)d_in[9];
  p.mw   = (const float*)d_in[10];
  p.vw   = (const float*)d_in[11];
  p.lcw  = (const float*)d_in[12];
  p.ldw  = (const float*)d_in[13];
  p.dwih = (const float*)d_in[14];
  p.dwhh = (const float*)d_in[15];
  p.dbih = (const float*)d_in[16];
  p.dbhh = (const float*)d_in[17];
  p.pw   = (const float*)d_in[18];
  p.pb   = (const float*)d_in[19];
  p.gw   = (const float*)d_in[20];
  p.gb   = (const float*)d_in[21];
  p.out  = (float*)d_out;
  p.ws   = (float*)d_ws;

  hipLaunchKernelGGL(init_kernel, dim3(1), dim3(512), 0, stream, p.ws);
  hipLaunchKernelGGL(decoder_kernel, dim3(512), dim3(1024), 0, stream, p);
}

// Round 9
// 39963.986 us; speedup vs baseline: 1.1291x; 1.1054x over previous
//
#include <hip/hip_runtime.h>

typedef _Float16 h16;
typedef _Float16 half8 __attribute__((ext_vector_type(8)));
typedef float f32x4 __attribute__((ext_vector_type(4)));

#define NEGV -1000000000.0f
#define MFMA16(a,b,c) __builtin_amdgcn_mfma_f32_16x16x32_f16(a,b,c,0,0,0)

struct Params {
  const float *memory, *dec_in; const int *memlen;
  const float *w1, *w2;
  const float *awih, *awhh, *abih, *abhh;
  const float *qw, *mw, *vw, *lcw, *ldw;
  const float *dwih, *dwhh, *dbih, *dbhh;
  const float *pw, *pb, *gw, *gb;
  float *out, *ws;
};

// ---- ws layout ----
// f16 arrays: offsets in HALFS
constexpr long long XALLF_H = 0;          // 400*32*256  xallf[t][b][256]
constexpr long long PMH_H   = 3276800;    // 32*128*384  pm[b][a][t]
constexpr long long PLB_H   = 4849664;    // 32*384*128  plb[b][t][a]
constexpr long long AWIHF_H = 6422528;    // 4096*768
constexpr long long AWHHF_H = 9568256;    // 4096*1024
constexpr long long DWIHF_H = 13762560;   // 4096*1536
constexpr long long DWHHF_H = 20054016;   // 4096*1024
constexpr long long LCWF_H  = 24248320;   // 32*64 (padded conv wts, f-major)
constexpr long long LDWF_H  = 24250368;   // 128*32 (a-major)
constexpr long long AHF_H   = 24254464;   // 2 * 32*1024 (double buffered)
constexpr long long DHF_H   = 24320000;   // 32*1024
constexpr long long CTXF_H  = 24352768;   // 32*512
// f16 read-only copies of per-step-streamed fp32 tensors (bytes halved):
constexpr long long MEMF_H  = 24812544;   // 32*384*512 memory (f16)
constexpr long long PWF_H   = 31104000;   // 80*1536 proj weights (f16)
constexpr long long QWF_H   = 31226880;   // 128*1024 query weights (f16)
// fp32 arrays: offsets in FLOATS
constexpr long long ZERO_F0 = 12127232;   // zero region start (covers AHF..DPART)
constexpr long long AC_F    = 12184576;   // 32*1024
constexpr long long DC_F    = 12217344;   // 32*1024
constexpr long long AW_F    = 12250112;   // 32*384
constexpr long long AWC_F   = 12262400;   // 32*384
constexpr long long DPART_F = 12274688;   // 32*4096
constexpr long long BAR_F   = 12405760;   // 512 uints
constexpr int  ZERO_LEN = 278528;
constexpr unsigned NBLK = 512;
// out layout
constexpr long long GATE0  = 1024000;
constexpr long long ALIGN0 = 1036800;

union SMem {
  float pmstage[12][512];                                     // 24.6 KB
  struct { float x[5][80]; float l1[5][256]; } pre;
  struct { float red[16][2][16][17]; } g;                     // 34.8 KB (16 waves)
  struct { float awseg[2][128]; h16 im2[96][72]; h16 locT[96][32];
           unsigned p16[96][64]; } ploc;                      // 45.6 KB (max)
  struct { float ah[1024]; float pq[128]; float pqp[8][128]; float vv[128];
           float e[384]; float w[384]; float red[32];
           float ctxred[4][256][2]; } row;                    // ~20 KB
  struct { float hc[1536]; float mp[80][8]; float gacc; } mel;
};

__device__ __forceinline__ float sigf(float x){ return 1.0f/(1.0f+__expf(-x)); }
__device__ __forceinline__ float tanhfast(float x){ float e2 = __expf(2.0f*x); return 1.0f - 2.0f/(e2+1.0f); }

// ---- agent-scope (cross-XCD coherent, cache-bypassing) accessors ----
__device__ __forceinline__ float aldf(const float* p){
  return __hip_atomic_load(p, __ATOMIC_RELAXED, __HIP_MEMORY_SCOPE_AGENT);
}
__device__ __forceinline__ void astf(float* p, float v){
  __hip_atomic_store(p, v, __ATOMIC_RELAXED, __HIP_MEMORY_SCOPE_AGENT);
}
__device__ __forceinline__ unsigned long long aldu64(const h16* p){
  return __hip_atomic_load((const unsigned long long*)p, __ATOMIC_RELAXED, __HIP_MEMORY_SCOPE_AGENT);
}
__device__ __forceinline__ half8 ald16(const h16* p){
  union { unsigned long long q[2]; half8 v; } u;
  u.q[0] = __hip_atomic_load((const unsigned long long*)p,     __ATOMIC_RELAXED, __HIP_MEMORY_SCOPE_AGENT);
  u.q[1] = __hip_atomic_load(((const unsigned long long*)p)+1, __ATOMIC_RELAXED, __HIP_MEMORY_SCOPE_AGENT);
  return u.v;
}
__device__ __forceinline__ void asth(h16* p, float v){
  union { h16 h; unsigned short s; } u; u.h = (h16)v;
  __hip_atomic_store((unsigned short*)p, u.s, __ATOMIC_RELAXED, __HIP_MEMORY_SCOPE_AGENT);
}
__device__ __forceinline__ void astu32(unsigned* p, unsigned v){
  __hip_atomic_store(p, v, __ATOMIC_RELAXED, __HIP_MEMORY_SCOPE_AGENT);
}

// software grid barrier; full=true adds release/acquire cache maintenance
__device__ __forceinline__ void gbar(unsigned* cnts, unsigned ep, bool full){
  __syncthreads();
  if (threadIdx.x == 0){
    if (full) __threadfence();
    __hip_atomic_fetch_add(&cnts[(blockIdx.x & 7)*64], 1u, __ATOMIC_RELEASE, __HIP_MEMORY_SCOPE_AGENT);
    const unsigned tgt = ep*NBLK;
    for (;;){
      unsigned s = 0;
      #pragma unroll
      for (int i = 0; i < 8; ++i)
        s += __hip_atomic_load(&cnts[i*64], __ATOMIC_RELAXED, __HIP_MEMORY_SCOPE_AGENT);
      if (s >= tgt) break;
      __builtin_amdgcn_s_sleep(4);
    }
    if (full) __threadfence();
  }
  __syncthreads();
}

__global__ void init_kernel(float* ws){
  unsigned* c = (unsigned*)(ws + BAR_F);
  if (threadIdx.x < 512) c[threadIdx.x] = 0u;
}

// 1024 threads/block (16 waves), 32 waves/CU. Broadcast-read dedup: att-LSTM
// and dec-partial merged to 128 blocks each with 2 A-tiles per wave sharing
// one B pair (4 MFMA / B-load) -> agent-scope B traffic halves (~28 MB/step).
__global__ __launch_bounds__(1024, 8)
void decoder_kernel(Params P){
  __shared__ SMem sm;
  const int tid = threadIdx.x;
  const int bid = blockIdx.x;
  float* ws = P.ws;
  h16*   wsh = (h16*)ws;
  unsigned* bar = (unsigned*)(ws + BAR_F);
  unsigned ep = 0;

  const int lane = tid & 63, wv = tid >> 6;          // wv in 0..15
  const int i16 = lane & 15, q = lane >> 4;

  // ============== PROLOGUE ==============
  {
    const long long gtid = (long long)bid*1024 + tid;
    const long long GS = 524288;
    for (long long i = gtid; i < ZERO_LEN; i += GS) ws[ZERO_F0 + i] = 0.f;
    for (long long i = gtid; i < 3145728; i += GS) wsh[AWIHF_H+i] = (h16)P.awih[i];
    for (long long i = gtid; i < 4194304; i += GS) wsh[AWHHF_H+i] = (h16)P.awhh[i];
    for (long long i = gtid; i < 6291456; i += GS) wsh[DWIHF_H+i] = (h16)P.dwih[i];
    for (long long i = gtid; i < 4194304; i += GS) wsh[DWHHF_H+i] = (h16)P.dwhh[i];
    for (long long i = gtid; i < 6291456; i += GS) wsh[MEMF_H+i] = (h16)P.memory[i];
    for (long long i = gtid; i < 122880; i += GS) wsh[PWF_H+i] = (h16)P.pw[i];
    for (long long i = gtid; i < 131072; i += GS) wsh[QWF_H+i] = (h16)P.qw[i];
    for (long long i = gtid; i < 2048; i += GS){
      int f = (int)(i >> 6), kk = (int)(i & 63), ch = kk >> 5, k = kk & 31;
      wsh[LCWF_H+i] = (k < 31) ? (h16)P.lcw[f*62 + ch*31 + k] : (h16)0.f;
    }
    for (long long i = gtid; i < 4096; i += GS) wsh[LDWF_H+i] = (h16)P.ldw[i];
  }
  // processed_memory -> PMH (f16)
  {
    const int b = bid >> 4, part = bid & 15;
    for (int sub = 0; sub < 2; ++sub){
      const int t0 = part*24 + sub*12;
      __syncthreads();
      for (int i = tid; i < 1536; i += 1024){
        int row = i >> 7, c4 = (i & 127) << 2;
        *reinterpret_cast<float4*>(&sm.pmstage[row][c4]) =
          *reinterpret_cast<const float4*>(P.memory + ((long long)(b*384 + t0 + row))*512 + c4);
      }
      __syncthreads();
      if (tid < 512){
        const int a = tid & 127, th = tid >> 7;
        float acc[3] = {0,0,0};
        const float* mwr = P.mw + (long long)a*512;
        for (int e = 0; e < 512; ++e){
          float wvv = mwr[e];
          #pragma unroll
          for (int jj = 0; jj < 3; ++jj) acc[jj] += wvv*sm.pmstage[th*3+jj][e];
        }
        #pragma unroll
        for (int jj = 0; jj < 3; ++jj)
          wsh[PMH_H + ((long long)b*128 + a)*384 + t0 + th*3 + jj] = (h16)acc[jj];
      }
    }
  }
  // prenet -> XALLF (f16)
  {
    for (int batch = 0; batch < 5; ++batch){
      const int pbase = bid*25 + batch*5;
      __syncthreads();
      for (int i = tid; i < 400; i += 1024){
        int j = i/80, m = i%80;
        int p = pbase + j; int tq = p >> 5, bb = p & 31;
        float v = 0.f;
        if (tq > 0) v = P.dec_in[((long long)bb*80 + m)*400 + (tq-1)];
        sm.pre.x[j][m] = v;
      }
      __syncthreads();
      {
        float acc[5] = {0,0,0,0,0};
        if (tid < 256){
          const float* w1r = P.w1 + (long long)tid*80;
          for (int m = 0; m < 80; ++m){
            float wvv = w1r[m];
            #pragma unroll
            for (int j = 0; j < 5; ++j) acc[j] += wvv*sm.pre.x[j][m];
          }
        }
        __syncthreads();
        if (tid < 256){
          #pragma unroll
          for (int j = 0; j < 5; ++j) sm.pre.l1[j][tid] = fmaxf(acc[j], 0.f);
        }
      }
      __syncthreads();
      if (tid < 256){
        float acc[5] = {0,0,0,0,0};
        const float* w2r = P.w2 + (long long)tid*256;
        for (int pp = 0; pp < 256; ++pp){
          float wvv = w2r[pp];
          #pragma unroll
          for (int j = 0; j < 5; ++j) acc[j] += wvv*sm.pre.l1[j][pp];
        }
        #pragma unroll
        for (int j = 0; j < 5; ++j){
          int p = pbase + j; int tq = p >> 5, bb = p & 31;
          wsh[XALLF_H + ((long long)tq*32 + bb)*256 + tid] = (h16)fmaxf(acc[j], 0.f);
        }
      }
    }
  }
  gbar(bar, ++ep, true);   // full fence once: weights/PMH/XALLF now visible + cached

  // ============== MAIN LOOP ==============
  for (int t = 0; t <= 400; ++t){
    const int cur = t & 1, prv = (t+1) & 1;

    // ---------- PHASE A ----------
    if (bid < 128){
      // att-LSTM: 8 units/block (128 blocks). 16 waves split 56 K-steps;
      // each step: TWO A rows (unit halves) x one B pair -> 4 MFMA.
      if (t < 400){
        const int u0 = bid*8;
        const int n = ((i16 >> 2)*1024) + u0 + (i16 & 3);   // h=0 row; h=1 = n+4
        f32x4 a00 = {0,0,0,0}, a01 = {0,0,0,0}, a10 = {0,0,0,0}, a11 = {0,0,0,0};
        const long long prvO = (long long)prv*32768;
        const int s0 = (wv*56) >> 4, s1 = ((wv+1)*56) >> 4;
        for (int s = s0; s < s1; ++s){
          const int k0 = s*32;
          const h16* base; long long stride4;
          if (k0 < 768){ base = wsh + AWIHF_H + (long long)n*768 + k0 + q*8;  stride4 = 4ll*768; }
          else         { base = wsh + AWHHF_H + (long long)n*1024 + (k0-768) + q*8; stride4 = 4ll*1024; }
          half8 A0 = *(const half8*)base;
          half8 A1 = *(const half8*)(base + stride4);
          half8 B0, B1;
          if (k0 < 256){
            B0 = *(const half8*)(wsh + XALLF_H + ((long long)t*32 + i16)*256 + k0 + q*8);
            B1 = *(const half8*)(wsh + XALLF_H + ((long long)t*32 + 16 + i16)*256 + k0 + q*8);
          } else if (k0 < 768){
            B0 = ald16(wsh + CTXF_H + i16*512 + (k0-256) + q*8);
            B1 = ald16(wsh + CTXF_H + (16+i16)*512 + (k0-256) + q*8);
          } else {
            B0 = ald16(wsh + AHF_H + prvO + i16*1024 + (k0-768) + q*8);
            B1 = ald16(wsh + AHF_H + prvO + (16+i16)*1024 + (k0-768) + q*8);
          }
          a00 = MFMA16(A0, B0, a00);
          a01 = MFMA16(A0, B1, a01);
          a10 = MFMA16(A1, B0, a10);
          a11 = MFMA16(A1, B1, a11);
        }
        // pass h=0 (units u0..u0+3)
        #pragma unroll
        for (int r = 0; r < 4; ++r){
          sm.g.red[wv][0][q*4+r][i16] = a00[r];
          sm.g.red[wv][1][q*4+r][i16] = a01[r];
        }
        __syncthreads();
        if (tid < 128){
          const int uu = tid >> 5, b = tid & 31;
          const int bt2 = b >> 4, c = b & 15;
          float g4[4];
          #pragma unroll
          for (int g = 0; g < 4; ++g){
            const int tr = g*4 + uu;
            float v = 0.f;
            #pragma unroll
            for (int w = 0; w < 16; ++w) v += sm.g.red[w][bt2][tr][c];
            const int ng = g*1024 + u0 + uu;
            g4[g] = v + P.abih[ng] + P.abhh[ng];
          }
          const long long idx = (long long)b*1024 + u0 + uu;
          float c2 = sigf(g4[1])*ws[AC_F + idx] + sigf(g4[0])*tanhfast(g4[2]);
          ws[AC_F + idx] = c2;
          asth(wsh + AHF_H + (long long)cur*32768 + idx, sigf(g4[3])*tanhfast(c2));
        }
        __syncthreads();
        // pass h=1 (units u0+4..u0+7)
        #pragma unroll
        for (int r = 0; r < 4; ++r){
          sm.g.red[wv][0][q*4+r][i16] = a10[r];
          sm.g.red[wv][1][q*4+r][i16] = a11[r];
        }
        __syncthreads();
        if (tid < 128){
          const int uu = tid >> 5, b = tid & 31;
          const int bt2 = b >> 4, c = b & 15;
          float g4[4];
          #pragma unroll
          for (int g = 0; g < 4; ++g){
            const int tr = g*4 + uu;
            float v = 0.f;
            #pragma unroll
            for (int w = 0; w < 16; ++w) v += sm.g.red[w][bt2][tr][c];
            const int ng = g*1024 + u0 + 4 + uu;
            g4[g] = v + P.abih[ng] + P.abhh[ng];
          }
          const long long idx = (long long)b*1024 + u0 + 4 + uu;
          float c2 = sigf(g4[1])*ws[AC_F + idx] + sigf(g4[0])*tanhfast(g4[2]);
          ws[AC_F + idx] = c2;
          asth(wsh + AHF_H + (long long)cur*32768 + idx, sigf(g4[3])*tanhfast(c2));
        }
      }
    } else if (bid >= 256 && bid < 384){
      // loc conv + dense via MFMA -> plb f16 [b][t][a]
      if (t < 400){
        const int pb = bid - 256, b = pb >> 2, tbase = (pb & 3)*96;
        for (int i = tid; i < 252; i += 1024){
          int ch = i / 126, ix = i % 126;
          int pos = tbase - 15 + ix;
          float v = 0.f;
          if (pos >= 0 && pos < 384)
            v = aldf(ws + (ch ? AWC_F : AW_F) + b*384 + pos);
          sm.ploc.awseg[ch][ix] = v;
        }
        __syncthreads();
        for (int i = tid; i < 96*64; i += 1024){
          int tt = i >> 6, kk = i & 63, ch = kk >> 5, k = kk & 31;
          sm.ploc.im2[tt][kk] = (k < 31) ? (h16)sm.ploc.awseg[ch][tt + k] : (h16)0.f;
        }
        __syncthreads();
        // conv: 12 tiles over 16 waves (4 idle)
        {
          int tile = wv;
          if (tile < 12){
            int tT = tile % 6, tF = tile / 6;
            f32x4 a = {0,0,0,0};
            #pragma unroll
            for (int ks = 0; ks < 2; ++ks){
              half8 A = *(const half8*)&sm.ploc.im2[tT*16 + i16][ks*32 + q*8];
              half8 B = *(const half8*)(wsh + LCWF_H + (tF*16 + i16)*64 + ks*32 + q*8);
              a = MFMA16(A, B, a);
            }
            #pragma unroll
            for (int r = 0; r < 4; ++r)
              sm.ploc.locT[tT*16 + q*4 + r][tF*16 + i16] = (h16)a[r];
          }
        }
        __syncthreads();
        // dense: 48 tiles over 16 waves = 3/wave
        unsigned short* s16 = (unsigned short*)&sm.ploc.p16[0][0];
        #pragma unroll
        for (int p = 0; p < 3; ++p){
          int tile = wv + p*16;
          int tT = tile % 6, tA = tile / 6;
          half8 A = *(const half8*)&sm.ploc.locT[tT*16 + i16][q*8];
          half8 B = *(const half8*)(wsh + LDWF_H + (tA*16 + i16)*32 + q*8);
          f32x4 a = {0,0,0,0};
          a = MFMA16(A, B, a);
          int aa = tA*16 + i16;
          union { unsigned long long u; h16 h[4]; } pmu;
          pmu.u = *(const unsigned long long*)
              (wsh + PMH_H + ((long long)b*128 + aa)*384 + tbase + tT*16 + q*4);
          #pragma unroll
          for (int r = 0; r < 4; ++r){
            union { h16 h; unsigned short s; } cv;
            cv.h = (h16)(a[r] + (float)pmu.h[r]);
            s16[(tT*16 + q*4 + r)*128 + aa] = cv.s;
          }
        }
        __syncthreads();
        unsigned* plbu = (unsigned*)(wsh + PLB_H);
        for (int i = tid; i < 96*64; i += 1024){
          int tt = i >> 6, a2 = i & 63;
          astu32(plbu + ((long long)b*384 + tbase + tt)*64 + a2, sm.ploc.p16[tt][a2]);
        }
      }
    } else if (bid >= 384){
      // dec-LSTM ctx-part (K=512) + cell for step t-1: 8 units/block.
      // 16 waves = 2 unit-quads x 8 K-eighths; A shared across B0/B1.
      if (t >= 1){
        const int u0 = (bid-384)*8;
        const int jt = wv & 1, kh = wv >> 1;          // kh in 0..7
        const int n = ((i16 >> 2)*1024) + u0 + jt*4 + (i16 & 3);
        f32x4 acc0 = {0,0,0,0}, acc1 = {0,0,0,0};
        for (int s = kh*2; s < kh*2 + 2; ++s){
          const int k0 = s*32;
          half8 A = *(const half8*)(wsh + DWIHF_H + (long long)n*1536 + 1024 + k0 + q*8);
          half8 B0 = ald16(wsh + CTXF_H + i16*512 + k0 + q*8);
          half8 B1 = ald16(wsh + CTXF_H + (16+i16)*512 + k0 + q*8);
          acc0 = MFMA16(A, B0, acc0);
          acc1 = MFMA16(A, B1, acc1);
        }
        #pragma unroll
        for (int r = 0; r < 4; ++r){
          sm.g.red[wv][0][q*4+r][i16] = acc0[r];
          sm.g.red[wv][1][q*4+r][i16] = acc1[r];
        }
        __syncthreads();
        if (tid < 256){
          const int uu8 = tid >> 5, b = tid & 31;
          const int j2 = uu8 >> 2, uu = uu8 & 3;
          const int bt = b >> 4, c = b & 15;
          const int unit = u0 + j2*4 + uu;
          float g4[4];
          #pragma unroll
          for (int g = 0; g < 4; ++g){
            const int tr = g*4 + uu;
            const int ng = g*1024 + unit;
            float v = 0.f;
            #pragma unroll
            for (int k = 0; k < 8; ++k) v += sm.g.red[j2 + 2*k][bt][tr][c];
            g4[g] = v + aldf(ws + DPART_F + (long long)b*4096 + ng)
                  + P.dbih[ng] + P.dbhh[ng];
          }
          const long long idx = (long long)b*1024 + unit;
          float c2 = sigf(g4[1])*ws[DC_F + idx] + sigf(g4[0])*tanhfast(g4[2]);
          ws[DC_F + idx] = c2;
          asth(wsh + DHF_H + idx, sigf(g4[3])*tanhfast(c2));
        }
      }
    }
    gbar(bar, ++ep, false);

    // ---------- PHASE B ----------
    if (bid < 32){
      // attention: pq, energies, softmax, ctx, aw/awc, alignments
      if (t < 400){
        const int b = bid;
        const int len = P.memlen[b];
        if (tid < 256){
          union { unsigned long long u; h16 h[4]; } hu;
          hu.u = aldu64(wsh + AHF_H + (long long)cur*32768 + b*1024 + tid*4);
          #pragma unroll
          for (int j = 0; j < 4; ++j) sm.row.ah[tid*4+j] = (float)hu.h[j];
        }
        if (tid < 128) sm.row.vv[tid] = P.vw[tid];
        __syncthreads();
        {
          // pq from f16 qw: 1024 threads = 8 K-eighths x 128 rows
          const int a = tid & 127, kh8 = tid >> 7;
          const h16* qr = wsh + QWF_H + (long long)a*1024 + kh8*128;
          const float* ahs = &sm.row.ah[kh8*128];
          float acc = 0.f;
          for (int k = 0; k < 128; k += 8){
            half8 wq = *(const half8*)(qr + k);
            acc += (float)wq[0]*ahs[k]   + (float)wq[1]*ahs[k+1]
                 + (float)wq[2]*ahs[k+2] + (float)wq[3]*ahs[k+3]
                 + (float)wq[4]*ahs[k+4] + (float)wq[5]*ahs[k+5]
                 + (float)wq[6]*ahs[k+6] + (float)wq[7]*ahs[k+7];
          }
          sm.row.pqp[kh8][a] = acc;
        }
        __syncthreads();
        if (tid < 128){
          float pqv = 0.f;
          #pragma unroll
          for (int k = 0; k < 8; ++k) pqv += sm.row.pqp[k][tid];
          sm.row.pq[tid] = pqv;
        }
        __syncthreads();
        // energies: one thread per t
        {
          const int tt = tid;
          if (tt < 384){
            float acc;
            if (tt < len){
              acc = 0.f;
              const unsigned long long* plp = (const unsigned long long*)
                  (wsh + PLB_H + ((long long)b*384 + tt)*128);
              for (int a0 = 0; a0 < 32; ++a0){
                union { unsigned long long u; h16 h[4]; } hu;
                hu.u = __hip_atomic_load(plp + a0, __ATOMIC_RELAXED, __HIP_MEMORY_SCOPE_AGENT);
                #pragma unroll
                for (int j = 0; j < 4; ++j)
                  acc += sm.row.vv[a0*4+j]*tanhfast(sm.row.pq[a0*4+j] + (float)hu.h[j]);
              }
            } else acc = NEGV;
            sm.row.e[tt] = acc;
          }
        }
        __syncthreads();
        float m = NEGV;
        for (int tt = tid; tt < 384; tt += 1024) m = fmaxf(m, sm.row.e[tt]);
        for (int o = 32; o; o >>= 1) m = fmaxf(m, __shfl_xor(m, o, 64));
        if ((tid & 63) == 0) sm.row.red[tid >> 6] = m;
        __syncthreads();
        float mx = sm.row.red[0];
        #pragma unroll
        for (int w = 1; w < 16; ++w) mx = fmaxf(mx, sm.row.red[w]);
        float s = 0.f;
        for (int tt = tid; tt < 384; tt += 1024){
          float wvv = (tt < len) ? __expf(sm.row.e[tt] - mx) : 0.f;
          sm.row.w[tt] = wvv; s += wvv;
        }
        for (int o = 32; o; o >>= 1) s += __shfl_xor(s, o, 64);
        if ((tid & 63) == 0) sm.row.red[16 + (tid >> 6)] = s;
        __syncthreads();
        float ssum = sm.row.red[16];
        #pragma unroll
        for (int w = 1; w < 16; ++w) ssum += sm.row.red[16+w];
        const float inv = 1.f/ssum;
        for (int tt = tid; tt < 384; tt += 1024){
          float wvv = sm.row.w[tt]*inv;
          sm.row.w[tt] = wvv;
          astf(ws + AW_F + b*384 + tt, wvv);
          float oldc = aldf(ws + AWC_F + b*384 + tt);
          astf(ws + AWC_F + b*384 + tt, oldc + wvv);
          P.out[ALIGN0 + ((long long)b*400 + t)*384 + tt] = wvv;
        }
        __syncthreads();
        // ctx from f16 memory: 1024 threads = 4 row-groups x 256 cols
        {
          const int col = tid & 255, rg = tid >> 8;
          const unsigned* mrow = (const unsigned*)(wsh + MEMF_H) + (long long)b*98304;
          float acc0 = 0.f, acc1 = 0.f;
          for (int t4 = rg*24; t4 < rg*24 + 24; ++t4){
            float4 w4 = *reinterpret_cast<const float4*>(&sm.row.w[t4*4]);
            const unsigned* m0 = mrow + t4*1024 + col;
            unsigned v0 = m0[0], v1 = m0[256], v2 = m0[512], v3 = m0[768];
            union { unsigned u; h16 h[2]; } d0, d1, d2, d3;
            d0.u = v0; d1.u = v1; d2.u = v2; d3.u = v3;
            acc0 += w4.x*(float)d0.h[0] + w4.y*(float)d1.h[0]
                  + w4.z*(float)d2.h[0] + w4.w*(float)d3.h[0];
            acc1 += w4.x*(float)d0.h[1] + w4.y*(float)d1.h[1]
                  + w4.z*(float)d2.h[1] + w4.w*(float)d3.h[1];
          }
          sm.row.ctxred[rg][col][0] = acc0;
          sm.row.ctxred[rg][col][1] = acc1;
          __syncthreads();
          if (tid < 256){
            union { h16 h[2]; unsigned u; } cv;
            cv.h[0] = (h16)(sm.row.ctxred[0][tid][0] + sm.row.ctxred[1][tid][0]
                          + sm.row.ctxred[2][tid][0] + sm.row.ctxred[3][tid][0]);
            cv.h[1] = (h16)(sm.row.ctxred[0][tid][1] + sm.row.ctxred[1][tid][1]
                          + sm.row.ctxred[2][tid][1] + sm.row.ctxred[3][tid][1]);
            astu32((unsigned*)(wsh + CTXF_H) + b*256 + tid, cv.u);
          }
        }
      }
    } else if (bid < 160){
      // dec-LSTM ah/dh partial (K=2048): 32 rows/block (128 blocks).
      // 16 waves split 64 K-steps (4 each); TWO A rows x one B pair -> 4 MFMA.
      if (t < 400){
        const int n0 = (bid-32)*32;
        const int n = n0 + i16;                       // rg=0 row; rg=1 = n+16
        f32x4 a00 = {0,0,0,0}, a01 = {0,0,0,0}, a10 = {0,0,0,0}, a11 = {0,0,0,0};
        const long long curO = (long long)cur*32768;
        for (int s = wv*4; s < wv*4 + 4; ++s){
          const int k0 = s*32;
          const h16* base; long long stride16;
          if (k0 < 1024){ base = wsh + DWIHF_H + (long long)n*1536 + k0 + q*8;        stride16 = 16ll*1536; }
          else          { base = wsh + DWHHF_H + (long long)n*1024 + (k0-1024) + q*8; stride16 = 16ll*1024; }
          half8 A0 = *(const half8*)base;
          half8 A1 = *(const half8*)(base + stride16);
          half8 B0, B1;
          if (k0 < 1024){
            B0 = ald16(wsh + AHF_H + curO + i16*1024 + k0 + q*8);
            B1 = ald16(wsh + AHF_H + curO + (16+i16)*1024 + k0 + q*8);
          } else {
            B0 = ald16(wsh + DHF_H + i16*1024 + (k0-1024) + q*8);
            B1 = ald16(wsh + DHF_H + (16+i16)*1024 + (k0-1024) + q*8);
          }
          a00 = MFMA16(A0, B0, a00);
          a01 = MFMA16(A0, B1, a01);
          a10 = MFMA16(A1, B0, a10);
          a11 = MFMA16(A1, B1, a11);
        }
        // pass rg=0 (rows n0..n0+15)
        #pragma unroll
        for (int r = 0; r < 4; ++r){
          sm.g.red[wv][0][q*4+r][i16] = a00[r];
          sm.g.red[wv][1][q*4+r][i16] = a01[r];
        }
        __syncthreads();
        if (tid < 256){
          const int r16 = tid & 15, c = tid >> 4;
          #pragma unroll
          for (int bt2 = 0; bt2 < 2; ++bt2){
            float v = 0.f;
            #pragma unroll
            for (int w = 0; w < 16; ++w) v += sm.g.red[w][bt2][r16][c];
            astf(ws + DPART_F + (long long)(bt2*16 + c)*4096 + n0 + r16, v);
          }
        }
        __syncthreads();
        // pass rg=1 (rows n0+16..n0+31)
        #pragma unroll
        for (int r = 0; r < 4; ++r){
          sm.g.red[wv][0][q*4+r][i16] = a10[r];
          sm.g.red[wv][1][q*4+r][i16] = a11[r];
        }
        __syncthreads();
        if (tid < 256){
          const int r16 = tid & 15, c = tid >> 4;
          #pragma unroll
          for (int bt2 = 0; bt2 < 2; ++bt2){
            float v = 0.f;
            #pragma unroll
            for (int w = 0; w < 16; ++w) v += sm.g.red[w][bt2][r16][c];
            astf(ws + DPART_F + (long long)(bt2*16 + c)*4096 + n0 + 16 + r16, v);
          }
        }
      }
    } else if (bid >= 288 && bid < 320){
      // mel + gate projections for step t-1; proj weights from f16 copy
      if (t >= 1){
        const int b = bid - 288;
        for (int i = tid; i < 384; i += 1024){
          union { unsigned long long u; h16 h[4]; } hu;
          hu.u = (i < 256) ? aldu64(wsh + DHF_H + b*1024 + i*4)
                           : aldu64(wsh + CTXF_H + b*512 + (i-256)*4);
          #pragma unroll
          for (int j = 0; j < 4; ++j) sm.mel.hc[i*4+j] = (float)hu.h[j];
        }
        __syncthreads();
        if (tid < 640){
          const int r = tid >> 3, h8 = tid & 7;      // 80 rows x 8 K-eighths
          const h16* pr = wsh + PWF_H + (long long)r*1536 + h8*192;
          const float* hcp = &sm.mel.hc[h8*192];
          float acc = 0.f;
          for (int k = 0; k < 192; k += 8){
            half8 wq = *(const half8*)(pr + k);
            acc += (float)wq[0]*hcp[k]   + (float)wq[1]*hcp[k+1]
                 + (float)wq[2]*hcp[k+2] + (float)wq[3]*hcp[k+3]
                 + (float)wq[4]*hcp[k+4] + (float)wq[5]*hcp[k+5]
                 + (float)wq[6]*hcp[k+6] + (float)wq[7]*hcp[k+7];
          }
          sm.mel.mp[r][h8] = acc;
        } else if (tid >= 768 && tid < 832){
          const int l = tid - 768;                   // wave 12, full wave
          const float* gp  = P.gw + l*24;
          const float* hcp = &sm.mel.hc[l*24];
          float acc = 0.f;
          #pragma unroll
          for (int k = 0; k < 24; ++k) acc += gp[k]*hcp[k];
          for (int o = 32; o; o >>= 1) acc += __shfl_xor(acc, o, 64);
          if (l == 0) sm.mel.gacc = acc;
        }
        __syncthreads();
        if (tid < 80){
          float v = P.pb[tid];
          #pragma unroll
          for (int k = 0; k < 8; ++k) v += sm.mel.mp[tid][k];
          P.out[((long long)b*80 + tid)*400 + (t-1)] = v;
        }
        if (tid == 80)
          P.out[GATE0 + (long long)b*400 + (t-1)] = sm.mel.gacc + P.gb[0];
      }
    }
    gbar(bar, ++ep, false);
  }
}

extern "C" void kernel_launch(void* const* d_in, const int* in_sizes, int n_in,
                              void* d_out, int out_size, void* d_ws, size_t ws_size,
                              hipStream_t stream) {
  (void)in_sizes; (void)n_in; (void)out_size; (void)ws_size;
  Params p;
  p.memory = (const float*)d_in[0];
  p.dec_in = (const float*)d_in[1];
  p.memlen = (const int*)d_in[2];
  p.w1   = (const float*)d_in[3];
  p.w2   = (const float*)d_in[4];
  p.awih = (const float*)d_in[5];
  p.awhh = (const float*)d_in[6];
  p.abih = (const float*)d_in[7];
  p.abhh = (const float*)d_in[8];
  p.qw   = (const float*)d_in[9];
  p.mw   = (const float*)d_in[10];
  p.vw   = (const float*)d_in[11];
  p.lcw  = (const float*)d_in[12];
  p.ldw  = (const float*)d_in[13];
  p.dwih = (const float*)d_in[14];
  p.dwhh = (const float*)d_in[15];
  p.dbih = (const float*)d_in[16];
  p.dbhh = (const float*)d_in[17];
  p.pw   = (const float*)d_in[18];
  p.pb   = (const float*)d_in[19];
  p.gw   = (const float*)d_in[20];
  p.gb   = (const float*)d_in[21];
  p.out  = (float*)d_out;
  p.ws   = (float*)d_ws;

  hipLaunchKernelGGL(init_kernel, dim3(1), dim3(512), 0, stream, p.ws);
  hipLaunchKernelGGL(decoder_kernel, dim3(512), dim3(1024), 0, stream, p);
}